// Round 3
// baseline (692.961 us; speedup 1.0000x reference)
//
#include <hip/hip_runtime.h>
#include <hip/hip_bf16.h>
#include <stdint.h>

#define EPSQ 1e-5f

typedef int i32x4 __attribute__((ext_vector_type(4)));

__device__ inline void gload16(const void* g, void* l){
  __builtin_amdgcn_global_load_lds((const __attribute__((address_space(1))) unsigned int*)g,
                                   (__attribute__((address_space(3))) unsigned int*)l, 16, 0, 0);
}

__device__ inline unsigned pack4(float4 v, float s, float lo, float hi){
  int a = (int)fminf(fmaxf(rintf(v.x*s), lo), hi);
  int b = (int)fminf(fmaxf(rintf(v.y*s), lo), hi);
  int c = (int)fminf(fmaxf(rintf(v.z*s), lo), hi);
  int d = (int)fminf(fmaxf(rintf(v.w*s), lo), hi);
  return (unsigned)((a&255)|((b&255)<<8)|((c&255)<<16)|((d&255)<<24));
}

// ---------------- mean|w| two-stage deterministic reduction ----------------
__global__ void absmean_partial(const float* __restrict__ w, int n4, double* __restrict__ partial){
  const float4* w4 = (const float4*)w;
  double s = 0.0;
  int idx = blockIdx.x*blockDim.x + threadIdx.x;
  int stride = gridDim.x*blockDim.x;
  for (int i = idx; i < n4; i += stride){
    float4 v = w4[i];
    s += (double)(fabsf(v.x)+fabsf(v.y)+fabsf(v.z)+fabsf(v.w));
  }
  __shared__ double sm[256];
  sm[threadIdx.x] = s; __syncthreads();
  for (int o=128;o>0;o>>=1){ if (threadIdx.x<o) sm[threadIdx.x]+=sm[threadIdx.x+o]; __syncthreads(); }
  if (threadIdx.x==0) partial[blockIdx.x] = sm[0];
}

__global__ void finalize_scales(const double* __restrict__ partial, float* __restrict__ scalebuf, double inv_n){
  __shared__ double sm[256];
  int t = threadIdx.x;
  double s1 = partial[t] + partial[t+256] + partial[t+512] + partial[t+768];
  sm[t]=s1; __syncthreads();
  for(int o=128;o>0;o>>=1){ if(t<o) sm[t]+=sm[t+o]; __syncthreads(); }
  double m1 = sm[0];
  __syncthreads();
  double s2 = partial[1024+t]+partial[1280+t]+partial[1536+t]+partial[1792+t];
  sm[t]=s2; __syncthreads();
  for(int o=128;o>0;o>>=1){ if(t<o) sm[t]+=sm[t+o]; __syncthreads(); }
  if (t==0){
    scalebuf[0] = 1.0f / fmaxf((float)(m1*inv_n),    EPSQ);   // s_w1
    scalebuf[1] = 1.0f / fmaxf((float)(sm[0]*inv_n), EPSQ);   // s_w2
  }
}

// ---------------- ternary weight quantization -> int8 {-1,0,1} ----------------
__global__ void wquant8(const float* __restrict__ w, char* __restrict__ wq,
                        const float* __restrict__ scalebuf, int which){
  int i = blockIdx.x*256 + threadIdx.x;          // i < nW/16, grid sized exactly
  float s = scalebuf[which];
  const float4* w4 = (const float4*)w;
  float4 v0 = w4[(size_t)i*4], v1 = w4[(size_t)i*4+1], v2 = w4[(size_t)i*4+2], v3 = w4[(size_t)i*4+3];
  uint4 pk = make_uint4(pack4(v0,s,-1.f,1.f), pack4(v1,s,-1.f,1.f),
                        pack4(v2,s,-1.f,1.f), pack4(v3,s,-1.f,1.f));
  *reinterpret_cast<uint4*>(wq + (size_t)i*16) = pk;
}

// ---------------- per-token activation scale (+optional int8 write) ----------------
__global__ void aquant8(const float* __restrict__ x, char* __restrict__ xq,
                        float* __restrict__ s_a, int* __restrict__ rowMax, int writeq){
  int m = blockIdx.x, t = threadIdx.x;           // 256 thr, D=2048
  if (t==0) rowMax[m] = 0;
  const float4* x4 = (const float4*)(x + (size_t)m*2048);
  float4 a = x4[t*2], b = x4[t*2+1];
  float va[8] = {a.x,a.y,a.z,a.w,b.x,b.y,b.z,b.w};
  float mx = 0.f;
  #pragma unroll
  for (int j=0;j<8;j++) mx = fmaxf(mx, fabsf(va[j]));
  #pragma unroll
  for (int o=1;o<64;o<<=1) mx = fmaxf(mx, __shfl_xor(mx, o, 64));
  __shared__ float wm[4];
  if ((t&63)==0) wm[t>>6] = mx;
  __syncthreads();
  mx = fmaxf(fmaxf(wm[0],wm[1]), fmaxf(wm[2],wm[3]));
  float s = 127.f / fmaxf(mx, EPSQ);
  if (t==0) s_a[m] = s;
  if (writeq){
    uint2 pk = make_uint2(pack4(a,s,-128.f,127.f), pack4(b,s,-128.f,127.f));
    *reinterpret_cast<uint2*>(xq + (size_t)m*2048 + t*8) = pk;
  }
}

// ---------------- per-row requant + GEMM2 epilogue scales ----------------
__global__ void rowscales(const int* __restrict__ rowMax, const float* __restrict__ s_a,
                          const float* __restrict__ scalebuf, float* __restrict__ rq,
                          float* __restrict__ inv2, int Mrows){
  int m = blockIdx.x*256 + threadIdx.x;
  if (m >= Mrows) return;
  int Mi = rowMax[m];
  float maxref = (float)Mi / (s_a[m]*scalebuf[0]);
  rq[m]   = (Mi > 0) ? 127.f/(float)Mi : 0.f;          // exact integer-domain requant
  inv2[m] = fmaxf(maxref, EPSQ) / (127.f*scalebuf[1]); // = 1/(sh*sw2)
}

// ---------------- i8 GEMM: C[m][n] = sum_k A[m][k]*B[n][k] ----------------
// 128x128 tile, BK=64 int8 (one 16x16x64 MFMA per frag per K-tile), 4 waves 2x2,
// LDS [128 rows][64B], 16B-chunk XOR swizzle: phys_chunk = logical ^ ((row>>1)&3).
// AF32: reg-stage A from f32 with per-row scale. BF32: reg-stage B from f32 with scalar scale.
// Else: direct global_load_lds from pre-quantized int8 (pre-swizzled global source).
// EPI 0: h32 = relu(acc) as f32 + per-row int max -> rowMax.  EPI 1: C = acc * rowScale[row].
template<int EPI, int AF32, int BF32>
__global__ __launch_bounds__(256) void gemm_i8(
    const void* __restrict__ Ap, const void* __restrict__ Bp, float* __restrict__ C,
    int N, int K, int* __restrict__ rowMax, const float* __restrict__ ascale,
    const float* __restrict__ rowScale, const float* __restrict__ scalebuf, int bwhich)
{
  __shared__ __align__(16) char smA[128*64];
  __shared__ __align__(16) char smB[128*64];
  __shared__ int smax[128];
  const int tid = threadIdx.x, lane = tid & 63;
  const int w = tid >> 6, wr = w >> 1, wc = w & 1;
  const int m0 = blockIdx.y*128, n0 = blockIdx.x*128;

  i32x4 acc[4][4] = {};

  // staging geometry: thread fills chunks (srow, *) and (srow+64, *); swizzle same for both
  const int srow = tid >> 2, scol = tid & 3;
  const int scl  = scol ^ ((srow >> 1) & 3);

  const char  *gA0=nullptr,*gA1=nullptr,*gB0=nullptr,*gB1=nullptr;
  const float *fA0=nullptr,*fA1=nullptr,*fB0=nullptr,*fB1=nullptr;
  float sA0=0.f, sA1=0.f, sB=0.f;
  if (AF32){
    fA0 = (const float*)Ap + (size_t)(m0+srow)*K    + scol*16;
    fA1 = (const float*)Ap + (size_t)(m0+srow+64)*K + scol*16;
    sA0 = ascale[m0+srow]; sA1 = ascale[m0+srow+64];
  } else {
    gA0 = (const char*)Ap + (size_t)(m0+srow)*K    + scl*16;
    gA1 = (const char*)Ap + (size_t)(m0+srow+64)*K + scl*16;
  }
  if (BF32){
    fB0 = (const float*)Bp + (size_t)(n0+srow)*K    + scol*16;
    fB1 = (const float*)Bp + (size_t)(n0+srow+64)*K + scol*16;
    sB  = scalebuf[bwhich];
  } else {
    gB0 = (const char*)Bp + (size_t)(n0+srow)*K    + scl*16;
    gB1 = (const char*)Bp + (size_t)(n0+srow+64)*K + scl*16;
  }

  const int frow = lane & 15, kb = lane >> 4;
  const int foff = (kb ^ ((frow >> 1) & 3)) * 16;

  for (int kt = 0; kt < K; kt += 64){
    __syncthreads();
    if (!AF32){
      gload16(gA0 + kt, smA + tid*16);
      gload16(gA1 + kt, smA + 4096 + tid*16);
    } else {
      const float4* s0 = (const float4*)(fA0 + kt);
      uint4 p0 = make_uint4(pack4(s0[0],sA0,-128.f,127.f), pack4(s0[1],sA0,-128.f,127.f),
                            pack4(s0[2],sA0,-128.f,127.f), pack4(s0[3],sA0,-128.f,127.f));
      *reinterpret_cast<uint4*>(smA + srow*64 + scl*16) = p0;
      const float4* s1 = (const float4*)(fA1 + kt);
      uint4 p1 = make_uint4(pack4(s1[0],sA1,-128.f,127.f), pack4(s1[1],sA1,-128.f,127.f),
                            pack4(s1[2],sA1,-128.f,127.f), pack4(s1[3],sA1,-128.f,127.f));
      *reinterpret_cast<uint4*>(smA + (srow+64)*64 + scl*16) = p1;
    }
    if (!BF32){
      gload16(gB0 + kt, smB + tid*16);
      gload16(gB1 + kt, smB + 4096 + tid*16);
    } else {
      const float4* s0 = (const float4*)(fB0 + kt);
      uint4 p0 = make_uint4(pack4(s0[0],sB,-1.f,1.f), pack4(s0[1],sB,-1.f,1.f),
                            pack4(s0[2],sB,-1.f,1.f), pack4(s0[3],sB,-1.f,1.f));
      *reinterpret_cast<uint4*>(smB + srow*64 + scl*16) = p0;
      const float4* s1 = (const float4*)(fB1 + kt);
      uint4 p1 = make_uint4(pack4(s1[0],sB,-1.f,1.f), pack4(s1[1],sB,-1.f,1.f),
                            pack4(s1[2],sB,-1.f,1.f), pack4(s1[3],sB,-1.f,1.f));
      *reinterpret_cast<uint4*>(smB + (srow+64)*64 + scl*16) = p1;
    }
    __syncthreads();
    i32x4 av[4], bv[4];
    #pragma unroll
    for (int fm=0;fm<4;fm++)
      av[fm] = *reinterpret_cast<const i32x4*>(smA + (wr*64+fm*16+frow)*64 + foff);
    #pragma unroll
    for (int fn=0;fn<4;fn++)
      bv[fn] = *reinterpret_cast<const i32x4*>(smB + (wc*64+fn*16+frow)*64 + foff);
    #pragma unroll
    for (int fm=0;fm<4;fm++)
      #pragma unroll
      for (int fn=0;fn<4;fn++)
        acc[fm][fn] = __builtin_amdgcn_mfma_i32_16x16x64_i8(av[fm], bv[fn], acc[fm][fn], 0,0,0);
  }

  if (EPI == 0){
    if (tid < 128) smax[tid] = 0;
    __syncthreads();
  }
  const int cc = lane & 15, cr = (lane >> 4)*4;
  #pragma unroll
  for (int fm=0;fm<4;fm++){
    #pragma unroll
    for (int reg=0;reg<4;reg++){
      int rl = wr*64 + fm*16 + cr + reg;
      size_t r = (size_t)(m0 + rl);
      if (EPI == 0){
        int rmax = 0;
        #pragma unroll
        for (int fn=0;fn<4;fn++){
          int v = acc[fm][fn][reg]; v = v > 0 ? v : 0;   // fused relu, exact int
          C[r*N + n0 + wc*64 + fn*16 + cc] = (float)v;
          rmax = v > rmax ? v : rmax;
        }
        atomicMax(&smax[rl], rmax);
      } else {
        float s = rowScale[r];
        #pragma unroll
        for (int fn=0;fn<4;fn++)
          C[r*N + n0 + wc*64 + fn*16 + cc] = (float)acc[fm][fn][reg] * s;
      }
    }
  }
  if (EPI == 0){
    __syncthreads();
    if (tid < 128) atomicMax(&rowMax[m0 + tid], smax[tid]);
  }
}

extern "C" void kernel_launch(void* const* d_in, const int* in_sizes, int n_in,
                              void* d_out, int out_size, void* d_ws, size_t ws_size,
                              hipStream_t stream){
  const float* x  = (const float*)d_in[0];
  const float* w1 = (const float*)d_in[1];
  const float* w2 = (const float*)d_in[2];
  float* out = (float*)d_out;

  const int DIM = 2048, INNER = 8192, MTOK = 8192;
  const size_t nW = (size_t)INNER*DIM;   // 16 MB int8 per weight

  char* ws = (char*)d_ws; size_t off = 0;
  auto alloc = [&](size_t n)->char*{ char* p = ws+off; off = (off+n+255) & ~(size_t)255; return p; };

  float* s_a     = (float*)alloc((size_t)MTOK*4);
  int*   rowMax  = (int*)  alloc((size_t)MTOK*4);
  float* rq      = (float*)alloc((size_t)MTOK*4);
  float* inv2    = (float*)alloc((size_t)MTOK*4);
  float* scalebuf= (float*)alloc(256);
  double* partial= (double*)alloc(2048*8);
  size_t tinyEnd = off;

  auto maxMc = [&](size_t fixed)->int{
    for (int m = 8192; m >= 128; m >>= 1)
      if (fixed + (size_t)m*INNER*4 + 256 <= ws_size) return m;
    return 0;
  };

  bool haveW=false, haveA=false; int Mc=0;
  if (tinyEnd + 2*nW + 512 + (size_t)128*INNER*4 + 256 <= ws_size){
    haveW = true;
    int McN = maxMc(tinyEnd + 2*nW + 512);
    int McA = maxMc(tinyEnd + 2*nW + 512 + (size_t)MTOK*DIM + 256);
    if (McA >= McN){ haveA = true; Mc = McA; } else Mc = McN;
  } else {
    Mc = maxMc(tinyEnd);
    if (!Mc) return;   // workspace absurdly small
  }
  char *w1q=nullptr, *w2q=nullptr, *a8=nullptr;
  if (haveW){ w1q = alloc(nW); w2q = alloc(nW); }
  if (haveA){ a8 = alloc((size_t)MTOK*DIM); }
  float* h32 = (float*)alloc((size_t)Mc*INNER*4);

  absmean_partial<<<1024,256,0,stream>>>(w1, (int)(nW/4), partial);
  absmean_partial<<<1024,256,0,stream>>>(w2, (int)(nW/4), partial+1024);
  finalize_scales<<<1,256,0,stream>>>(partial, scalebuf, 1.0/(double)nW);
  if (haveW){
    wquant8<<<(int)(nW/16/256),256,0,stream>>>(w1, w1q, scalebuf, 0);
    wquant8<<<(int)(nW/16/256),256,0,stream>>>(w2, w2q, scalebuf, 1);
  }
  aquant8<<<MTOK,256,0,stream>>>(x, a8, s_a, rowMax, haveA?1:0);

  for (int ch = 0; ch < MTOK; ch += Mc){
    dim3 g1(INNER/128, Mc/128), g2(DIM/128, Mc/128);
    if (haveA)
      gemm_i8<0,0,0><<<g1,256,0,stream>>>(a8 + (size_t)ch*DIM, w1q, h32, INNER, DIM,
                                          rowMax+ch, nullptr, nullptr, scalebuf, 0);
    else if (haveW)
      gemm_i8<0,1,0><<<g1,256,0,stream>>>(x + (size_t)ch*DIM, w1q, h32, INNER, DIM,
                                          rowMax+ch, s_a+ch, nullptr, scalebuf, 0);
    else
      gemm_i8<0,1,1><<<g1,256,0,stream>>>(x + (size_t)ch*DIM, w1, h32, INNER, DIM,
                                          rowMax+ch, s_a+ch, nullptr, scalebuf, 0);

    rowscales<<<(Mc+255)/256,256,0,stream>>>(rowMax+ch, s_a+ch, scalebuf, rq+ch, inv2+ch, Mc);

    if (haveW)
      gemm_i8<1,1,0><<<g2,256,0,stream>>>(h32, w2q, out + (size_t)ch*DIM, DIM, INNER,
                                          nullptr, rq+ch, inv2+ch, scalebuf, 1);
    else
      gemm_i8<1,1,1><<<g2,256,0,stream>>>(h32, w2, out + (size_t)ch*DIM, DIM, INNER,
                                          nullptr, rq+ch, inv2+ch, scalebuf, 1);
  }
}

// Round 4
// 570.117 us; speedup vs baseline: 1.2155x; 1.2155x over previous
//
#include <hip/hip_runtime.h>
#include <hip/hip_bf16.h>
#include <stdint.h>

#define EPSQ 1e-5f

typedef int i32x4 __attribute__((ext_vector_type(4)));

__device__ inline void gload16(const void* g, void* l){
  __builtin_amdgcn_global_load_lds((const __attribute__((address_space(1))) unsigned int*)g,
                                   (__attribute__((address_space(3))) unsigned int*)l, 16, 0, 0);
}

__device__ inline unsigned pack4(float4 v, float s, float lo, float hi){
  int a = (int)fminf(fmaxf(rintf(v.x*s), lo), hi);
  int b = (int)fminf(fmaxf(rintf(v.y*s), lo), hi);
  int c = (int)fminf(fmaxf(rintf(v.z*s), lo), hi);
  int d = (int)fminf(fmaxf(rintf(v.w*s), lo), hi);
  return (unsigned)((a&255)|((b&255)<<8)|((c&255)<<16)|((d&255)<<24));
}

// ---------------- mean|w| two-stage deterministic reduction ----------------
__global__ void absmean_partial(const float* __restrict__ w, int n4, double* __restrict__ partial){
  const float4* w4 = (const float4*)w;
  double s = 0.0;
  int idx = blockIdx.x*blockDim.x + threadIdx.x;
  int stride = gridDim.x*blockDim.x;
  for (int i = idx; i < n4; i += stride){
    float4 v = w4[i];
    s += (double)(fabsf(v.x)+fabsf(v.y)+fabsf(v.z)+fabsf(v.w));
  }
  __shared__ double sm[256];
  sm[threadIdx.x] = s; __syncthreads();
  for (int o=128;o>0;o>>=1){ if (threadIdx.x<o) sm[threadIdx.x]+=sm[threadIdx.x+o]; __syncthreads(); }
  if (threadIdx.x==0) partial[blockIdx.x] = sm[0];
}

__global__ void finalize_scales(const double* __restrict__ partial, float* __restrict__ scalebuf, double inv_n){
  __shared__ double sm[256];
  int t = threadIdx.x;
  double s1 = partial[t] + partial[t+256] + partial[t+512] + partial[t+768];
  sm[t]=s1; __syncthreads();
  for(int o=128;o>0;o>>=1){ if(t<o) sm[t]+=sm[t+o]; __syncthreads(); }
  double m1 = sm[0];
  __syncthreads();
  double s2 = partial[1024+t]+partial[1280+t]+partial[1536+t]+partial[1792+t];
  sm[t]=s2; __syncthreads();
  for(int o=128;o>0;o>>=1){ if(t<o) sm[t]+=sm[t+o]; __syncthreads(); }
  if (t==0){
    scalebuf[0] = 1.0f / fmaxf((float)(m1*inv_n),    EPSQ);   // s_w1
    scalebuf[1] = 1.0f / fmaxf((float)(sm[0]*inv_n), EPSQ);   // s_w2
  }
}

// ---------------- ternary weight quantization -> int8 {-1,0,1} ----------------
__global__ void wquant8(const float* __restrict__ w, char* __restrict__ wq,
                        const float* __restrict__ scalebuf, int which){
  int i = blockIdx.x*256 + threadIdx.x;
  float s = scalebuf[which];
  const float4* w4 = (const float4*)w;
  float4 v0 = w4[(size_t)i*4], v1 = w4[(size_t)i*4+1], v2 = w4[(size_t)i*4+2], v3 = w4[(size_t)i*4+3];
  uint4 pk = make_uint4(pack4(v0,s,-1.f,1.f), pack4(v1,s,-1.f,1.f),
                        pack4(v2,s,-1.f,1.f), pack4(v3,s,-1.f,1.f));
  *reinterpret_cast<uint4*>(wq + (size_t)i*16) = pk;
}

// ---------------- per-token activation quant -> int8 + scale + rowMax init ----------------
__global__ void aquant8(const float* __restrict__ x, char* __restrict__ xq,
                        float* __restrict__ s_a, int* __restrict__ rowMax){
  int m = blockIdx.x, t = threadIdx.x;           // 256 thr, D=2048
  if (t==0) rowMax[m] = 0;
  const float4* x4 = (const float4*)(x + (size_t)m*2048);
  float4 a = x4[t*2], b = x4[t*2+1];
  float va[8] = {a.x,a.y,a.z,a.w,b.x,b.y,b.z,b.w};
  float mx = 0.f;
  #pragma unroll
  for (int j=0;j<8;j++) mx = fmaxf(mx, fabsf(va[j]));
  #pragma unroll
  for (int o=1;o<64;o<<=1) mx = fmaxf(mx, __shfl_xor(mx, o, 64));
  __shared__ float wm[4];
  if ((t&63)==0) wm[t>>6] = mx;
  __syncthreads();
  mx = fmaxf(fmaxf(wm[0],wm[1]), fmaxf(wm[2],wm[3]));
  float s = 127.f / fmaxf(mx, EPSQ);
  if (t==0) s_a[m] = s;
  uint2 pk = make_uint2(pack4(a,s,-128.f,127.f), pack4(b,s,-128.f,127.f));
  *reinterpret_cast<uint2*>(xq + (size_t)m*2048 + t*8) = pk;
}

// ---------------- i8 GEMM, 128x128 tile, BK=64, 2-phase dbuf pipeline ----------------
// A,B int8 via global_load_lds (pre-swizzled source, linear LDS dest).
// K-extent per dispatch is fixed 2048 (GEMM1 full-K; GEMM2 one K-slice, kbase=z*2048).
// EPI 0: h16[r][n] = min(relu(acc),65535) + per-row int max -> rowMax (LDS-reduced).
// EPI 1: atomicAdd int32 partials into C (deterministic integer accumulation).
template<int EPI>
__global__ __launch_bounds__(256) void gemm_i8(
    const char* __restrict__ A, int lda, const char* __restrict__ B, int ldb,
    void* __restrict__ Cv, int N, int* __restrict__ rowMax)
{
  __shared__ __align__(16) char smA[2*128*64];
  __shared__ __align__(16) char smB[2*128*64];
  __shared__ int smax[128];
  const int tid = threadIdx.x, lane = tid & 63;
  const int w = tid >> 6, wr = w >> 1, wc = w & 1;
  const int m0 = blockIdx.y*128, n0 = blockIdx.x*128;
  const int kbase = blockIdx.z*2048;

  i32x4 acc[4][4] = {};

  // staging: thread fills 16B chunk (srow, scl) and (srow+64, scl); 64B rows, 4 chunks/row
  const int srow = tid >> 2, scol = tid & 3;
  const int scl  = scol ^ ((srow >> 1) & 3);          // XOR swizzle (write side, via source)
  const char* gA = A + (size_t)(m0+srow)*lda + kbase + scl*16;
  const char* gB = B + (size_t)(n0+srow)*ldb + kbase + scl*16;
  const size_t a64 = (size_t)64*lda, b64 = (size_t)64*ldb;

  const int frow = lane & 15, kb = lane >> 4;
  const int foff = (kb ^ ((frow >> 1) & 3)) * 16;     // read-side swizzle

  auto stage = [&](int buf, int t){
    char* dA = smA + buf*8192 + tid*16;
    char* dB = smB + buf*8192 + tid*16;
    gload16(gA + t*64,       dA);
    gload16(gA + t*64 + a64, dA + 4096);
    gload16(gB + t*64,       dB);
    gload16(gB + t*64 + b64, dB + 4096);
  };

  stage(0, 0);
  __syncthreads();                                    // drains vmcnt + barrier
  int cur = 0;
  for (int t = 0; t < 32; ++t){
    if (t < 31) stage(cur^1, t+1);                    // prefetch next tile (in flight during MFMA)
    i32x4 av[4], bv[4];
    #pragma unroll
    for (int fm=0;fm<4;fm++)
      av[fm] = *reinterpret_cast<const i32x4*>(smA + cur*8192 + (wr*64+fm*16+frow)*64 + foff);
    #pragma unroll
    for (int fn=0;fn<4;fn++)
      bv[fn] = *reinterpret_cast<const i32x4*>(smB + cur*8192 + (wc*64+fn*16+frow)*64 + foff);
    #pragma unroll
    for (int fm=0;fm<4;fm++)
      #pragma unroll
      for (int fn=0;fn<4;fn++)
        acc[fm][fn] = __builtin_amdgcn_mfma_i32_16x16x64_i8(av[fm], bv[fn], acc[fm][fn], 0,0,0);
    if (t < 31){ __syncthreads(); cur ^= 1; }
  }

  if (EPI == 0){
    if (tid < 128) smax[tid] = 0;
    __syncthreads();
  }
  const int cc = lane & 15, cr = (lane >> 4)*4;
  #pragma unroll
  for (int fm=0;fm<4;fm++){
    #pragma unroll
    for (int reg=0;reg<4;reg++){
      int rl = wr*64 + fm*16 + cr + reg;
      size_t r = (size_t)(m0 + rl);
      if (EPI == 0){
        ushort* C16 = (ushort*)Cv;
        int rmax = 0;
        #pragma unroll
        for (int fn=0;fn<4;fn++){
          int v = acc[fm][fn][reg]; v = v > 0 ? v : 0;        // fused relu, exact int
          C16[r*N + n0 + wc*64 + fn*16 + cc] = (ushort)(v > 65535 ? 65535 : v);
          rmax = v > rmax ? v : rmax;
        }
        atomicMax(&smax[rl], rmax);
      } else {
        int* Ci = (int*)Cv;
        #pragma unroll
        for (int fn=0;fn<4;fn++)
          atomicAdd(&Ci[r*N + n0 + wc*64 + fn*16 + cc], acc[fm][fn][reg]);
      }
    }
  }
  if (EPI == 0){
    __syncthreads();
    if (tid < 128) atomicMax(&rowMax[m0 + tid], smax[tid]);
  }
}

// ---------------- h16 -> int8 requant (rq = 127/Mi, exact integer domain) ----------------
__global__ void hquant(const ushort* __restrict__ h16, char* __restrict__ hq,
                       const int* __restrict__ rowMax){
  int m = blockIdx.y;
  int Mi = rowMax[m];
  float rqv = (Mi > 0) ? 127.f/(float)Mi : 0.f;
  size_t base = (size_t)m*8192 + blockIdx.x*2048 + threadIdx.x*8;
  uint4 pk = *reinterpret_cast<const uint4*>(h16 + base);
  unsigned u[4] = {pk.x, pk.y, pk.z, pk.w};
  unsigned o[2] = {0,0};
  #pragma unroll
  for (int j=0;j<8;j++){
    float h = (float)(u[j>>1] >> ((j&1)*16) & 0xffff);
    int q = (int)fminf(rintf(h*rqv), 127.f);            // h >= 0
    o[j>>2] |= (unsigned)(q & 255) << ((j&3)*8);
  }
  *reinterpret_cast<uint2*>(hq + base) = make_uint2(o[0], o[1]);
}

// ---------------- int32 accum -> f32 out, per-row scale (in-place) ----------------
__global__ void convert_out(float* __restrict__ out, const int* __restrict__ rowMax,
                            const float* __restrict__ s_a, const float* __restrict__ scalebuf){
  int m = blockIdx.x, t = threadIdx.x;
  int Mi = rowMax[m];
  float maxref = (float)Mi / (s_a[m]*scalebuf[0]);
  float inv2 = fmaxf(maxref, EPSQ) / (127.f*scalebuf[1]);
  int* p = (int*)(out + (size_t)m*2048);
  int4 a = ((const int4*)p)[t*2], b = ((const int4*)p)[t*2+1];
  float4 fa = make_float4((float)a.x*inv2, (float)a.y*inv2, (float)a.z*inv2, (float)a.w*inv2);
  float4 fb = make_float4((float)b.x*inv2, (float)b.y*inv2, (float)b.z*inv2, (float)b.w*inv2);
  ((float4*)p)[t*2] = fa; ((float4*)p)[t*2+1] = fb;
}

extern "C" void kernel_launch(void* const* d_in, const int* in_sizes, int n_in,
                              void* d_out, int out_size, void* d_ws, size_t ws_size,
                              hipStream_t stream){
  const float* x  = (const float*)d_in[0];
  const float* w1 = (const float*)d_in[1];
  const float* w2 = (const float*)d_in[2];
  float* out = (float*)d_out;

  const int DIM = 2048, INNER = 8192, MTOK = 8192;
  const size_t nW = (size_t)INNER*DIM;   // 16 MB int8 per weight

  char* ws = (char*)d_ws; size_t off = 0;
  auto alloc = [&](size_t n)->char*{ char* p = ws+off; off = (off+n+255) & ~(size_t)255; return p; };

  float*  s_a     = (float*)alloc((size_t)MTOK*4);
  int*    rowMax  = (int*)  alloc((size_t)MTOK*4);
  float*  scalebuf= (float*)alloc(256);
  double* partial = (double*)alloc(2048*8);
  char*   w1q     = alloc(nW);
  char*   w2q     = alloc(nW);
  char*   a8      = alloc((size_t)MTOK*DIM);

  // chunk buffers: h16 (u16, Mc x INNER) + hq (int8, Mc x INNER)
  int Mc = 0;
  for (int m = 8192; m >= 128; m >>= 1)
    if (off + (size_t)m*INNER*3 + 1024 <= ws_size){ Mc = m; break; }
  if (!Mc) return;
  ushort* h16 = (ushort*)alloc((size_t)Mc*INNER*2);
  char*   hq  = alloc((size_t)Mc*INNER);

  absmean_partial<<<1024,256,0,stream>>>(w1, (int)(nW/4), partial);
  absmean_partial<<<1024,256,0,stream>>>(w2, (int)(nW/4), partial+1024);
  finalize_scales<<<1,256,0,stream>>>(partial, scalebuf, 1.0/(double)nW);
  wquant8<<<(int)(nW/16/256),256,0,stream>>>(w1, w1q, scalebuf, 0);
  wquant8<<<(int)(nW/16/256),256,0,stream>>>(w2, w2q, scalebuf, 1);
  aquant8<<<MTOK,256,0,stream>>>(x, a8, s_a, rowMax);

  for (int ch = 0; ch < MTOK; ch += Mc){
    // GEMM1: [Mc x 2048] x [8192 x 2048]^T -> h16, rowMax
    gemm_i8<0><<<dim3(INNER/128, Mc/128, 1),256,0,stream>>>(
        a8 + (size_t)ch*DIM, DIM, w1q, DIM, h16, INNER, rowMax + ch);
    // requant h -> int8
    hquant<<<dim3(INNER/2048, Mc),256,0,stream>>>(h16, hq, rowMax + ch);
    // GEMM2 (K-split x4, int32 atomic accumulation in d_out)
    hipMemsetAsync(out + (size_t)ch*DIM, 0, (size_t)Mc*DIM*4, stream);
    gemm_i8<1><<<dim3(DIM/128, Mc/128, INNER/2048),256,0,stream>>>(
        hq, INNER, w2q, INNER, out + (size_t)ch*DIM, DIM, nullptr);
    // scale to f32 (in-place)
    convert_out<<<Mc,256,0,stream>>>(out + (size_t)ch*DIM, rowMax + ch, s_a + ch, scalebuf);
  }
}